// Round 4
// baseline (114.979 us; speedup 1.0000x reference)
//
#include <hip/hip_runtime.h>
#include <math.h>

#define CC 1024
#define SS 16
#define DD 512
#define RR (CC*SS)
#define EPSV 1e-8f
#define LDB 520   // 512 shorts + 8 pad -> stride 260 dwords (4 mod 32)

typedef __attribute__((ext_vector_type(8))) short short8;
typedef __attribute__((ext_vector_type(4))) float f32x4;
typedef unsigned short ushort_t;

__device__ __forceinline__ unsigned short f2bf(float f) {
  unsigned u = __float_as_uint(f);
  u += 0x7fffu + ((u >> 16) & 1u);       // RNE
  return (unsigned short)(u >> 16);
}

__device__ __forceinline__ void async16(void* l, const void* g) {
  __builtin_amdgcn_global_load_lds(
      (const __attribute__((address_space(1))) void*)g,
      (__attribute__((address_space(3))) void*)l, 16, 0, 0);
}

__device__ __forceinline__ float softplusf(float v) {
  return (v > 20.f) ? v : log1pf(expf(v));
}

// ---------------- Kernel 1: per-class precompute ----------------
__global__ __launch_bounds__(256) void k_pre(
    const float* __restrict__ x, unsigned* __restrict__ mn,
    float* __restrict__ nx, float* __restrict__ simpos,
    ushort_t* __restrict__ xn) {
  __shared__ float xs[SS * DD];
  __shared__ float sums[DD];
  __shared__ float red[4];
  __shared__ float snm;
  __shared__ float rinv[SS];
  const int j = blockIdx.x, tid = threadIdx.x;
  const float4* xj = (const float4*)(x + (size_t)j * SS * DD);
  float4* xs4 = (float4*)xs;
  for (int i = tid; i < SS * DD / 4; i += 256) xs4[i] = xj[i];
  __syncthreads();
  float m2 = 0.f;
  {
    const int d0 = tid * 2;   // 256 threads x 2 cols = 512
    float s0 = 0.f, s1 = 0.f;
#pragma unroll
    for (int i = 0; i < SS; ++i) {
      s0 += xs[i * DD + d0];
      s1 += xs[i * DD + d0 + 1];
    }
    sums[d0] = s0; sums[d0 + 1] = s1;
    float ma = s0 * (1.0f / SS), mb = s1 * (1.0f / SS);
    m2 = fmaf(ma, ma, mb * mb);
  }
#pragma unroll
  for (int off = 32; off > 0; off >>= 1) m2 += __shfl_xor(m2, off, 64);
  const int wid = tid >> 6, lane = tid & 63;
  if (lane == 0) red[wid] = m2;
  __syncthreads();
  if (tid == 0) snm = sqrtf(red[0] + red[1] + red[2] + red[3]);
  __syncthreads();
  const float inm = (1.0f / SS) / snm;
  {
    const int d0 = tid * 2;
    unsigned lo = f2bf(sums[d0] * inm);
    unsigned hi = f2bf(sums[d0 + 1] * inm);
    mn[((size_t)j * DD + d0) >> 1] = lo | (hi << 16);
  }
  for (int i = wid; i < SS; i += 4) {
    float nx2 = 0.f, dxs = 0.f, t2 = 0.f;
    for (int d = lane; d < DD; d += 64) {
      float xv = xs[i * DD + d];
      float sc = sums[d];
      nx2 = fmaf(xv, xv, nx2);
      dxs = fmaf(xv, sc, dxs);
      float tv = sc - xv;
      t2 = fmaf(tv, tv, t2);
    }
#pragma unroll
    for (int off = 32; off > 0; off >>= 1) {
      nx2 += __shfl_xor(nx2, off, 64);
      dxs += __shfl_xor(dxs, off, 64);
      t2  += __shfl_xor(t2,  off, 64);
    }
    if (lane == 0) {
      float nxv = sqrtf(nx2);
      float tn  = sqrtf(t2);
      float num = (dxs - nx2) * (1.0f / (SS - 1));
      float den = fmaxf(nxv * tn * (1.0f / (SS - 1)), EPSV);
      nx[j * SS + i] = nxv;
      rinv[i] = 1.0f / nxv;
      simpos[j * SS + i] = num / den;
    }
  }
  __syncthreads();
  if (xn) {
    uint2* dst = (uint2*)(xn + (size_t)j * SS * DD);
    for (int idx = tid; idx < SS * DD / 4; idx += 256) {
      const int e = idx * 4;                 // all 4 in same row (DD=512)
      const float ri = rinv[e >> 9];
      unsigned a = f2bf(xs[e] * ri),     b2 = f2bf(xs[e + 1] * ri);
      unsigned c = f2bf(xs[e + 2] * ri), d2 = f2bf(xs[e + 3] * ri);
      dst[idx] = make_uint2(a | (b2 << 16), c | (d2 << 16));
    }
  }
}

// ---------------- Kernel 2: MFMA GEMM + fused exp-sum ----------------
// grid = 128 row-blocks x 4 col-splits = 512 blocks, 256 threads.
// Block: 128 rows (4 waves x 2 row-tiles of 16), 256 cols in 8 chunks of
// 32, B double-buffered (2 x 33.3 KB = 66.5 KB -> 2 blocks/CU).
// __launch_bounds__(256,2): cap 256 VGPR so af[2][16] stays resident.
template <bool USE_XN>
__global__ __launch_bounds__(256, 2) void k_gemm(
    const float* __restrict__ x, const ushort_t* __restrict__ xn,
    const ushort_t* __restrict__ mn, const float* __restrict__ nx,
    const float* __restrict__ simpos, const float* __restrict__ wptr,
    const float* __restrict__ bptr, float* __restrict__ ps) {
  __shared__ ushort_t bs[2][32 * LDB];   // 66.5 KB
  const int tid = threadIdx.x;
  const int wid = tid >> 6, lane = tid & 63;
  const int cL = lane & 15, quad = lane >> 4;
  const int rb = (int)blockIdx.x >> 2, cb = (int)blockIdx.x & 3;
  const int r0 = rb * 128, cbase = cb * 256;
  const float wp = softplusf(wptr[0]), bv = bptr[0];

  short8 af[2][16];
  int jw[2];
  float sp[2][4], sacc[2][4];
#pragma unroll
  for (int rt = 0; rt < 2; ++rt) {
    const int row = r0 + wid * 32 + rt * 16 + cL;
    if (USE_XN) {
      const short8* src = (const short8*)(xn + (size_t)row * DD);
#pragma unroll
      for (int kc = 0; kc < 16; ++kc) af[rt][kc] = src[kc * 4 + quad];
    } else {
      const float* xr = x + (size_t)row * DD;
      const float invn = 1.0f / nx[row];
#pragma unroll
      for (int kc = 0; kc < 16; ++kc) {
        const int k0 = kc * 32 + quad * 8;
        float4 p = *(const float4*)(xr + k0);
        float4 q = *(const float4*)(xr + k0 + 4);
        short8 v;
        v[0] = f2bf(p.x * invn); v[1] = f2bf(p.y * invn);
        v[2] = f2bf(p.z * invn); v[3] = f2bf(p.w * invn);
        v[4] = f2bf(q.x * invn); v[5] = f2bf(q.y * invn);
        v[6] = f2bf(q.z * invn); v[7] = f2bf(q.w * invn);
        af[rt][kc] = v;
      }
    }
    jw[rt] = (r0 + wid * 32 + rt * 16) >> 4;
#pragma unroll
    for (int r = 0; r < 4; ++r) {
      sp[rt][r] = simpos[r0 + wid * 32 + rt * 16 + quad * 4 + r];
      sacc[rt][r] = 0.f;
    }
  }

  // stage chunk 0 (32 mn rows, 8 rows per wave)
  {
    const ushort_t* gsrc = mn + (size_t)cbase * DD;
#pragma unroll
    for (int t = 0; t < 8; ++t) {
      const int rr = wid + t * 4;
      async16(&bs[0][rr * LDB + lane * 8], gsrc + (size_t)rr * DD + lane * 8);
    }
  }
  __syncthreads();

  for (int cc = 0; cc < 8; ++cc) {
    if (cc < 7) {
      const ushort_t* gsrc = mn + (size_t)(cbase + (cc + 1) * 32) * DD;
      ushort_t* dst = bs[(cc + 1) & 1];
#pragma unroll
      for (int t = 0; t < 8; ++t) {
        const int rr = wid + t * 4;
        async16(&dst[rr * LDB + lane * 8], gsrc + (size_t)rr * DD + lane * 8);
      }
    }
    const ushort_t* B = bs[cc & 1];
    f32x4 acc[2][2];
#pragma unroll
    for (int rt = 0; rt < 2; ++rt)
#pragma unroll
      for (int f = 0; f < 2; ++f) acc[rt][f] = (f32x4){0.f, 0.f, 0.f, 0.f};
#pragma unroll
    for (int kc = 0; kc < 16; ++kc) {
      short8 bfr[2];
#pragma unroll
      for (int f = 0; f < 2; ++f)
        bfr[f] = *(const short8*)&B[(f * 16 + cL) * LDB + kc * 32 + quad * 8];
#pragma unroll
      for (int rt = 0; rt < 2; ++rt)
#pragma unroll
        for (int f = 0; f < 2; ++f)
          acc[rt][f] = __builtin_amdgcn_mfma_f32_16x16x32_bf16(
              af[rt][kc], bfr[f], acc[rt][f], 0, 0, 0);
    }
    const int c0 = cbase + cc * 32;
#pragma unroll
    for (int rt = 0; rt < 2; ++rt)
#pragma unroll
      for (int f = 0; f < 2; ++f) {
        const int cg = c0 + f * 16 + cL;
        const bool diag = (cg == jw[rt]);
#pragma unroll
        for (int r = 0; r < 4; ++r) {
          const float sim = diag ? sp[rt][r] : acc[rt][f][r];
          sacc[rt][r] += __expf(fmaf(wp, sim, bv));
        }
      }
    __syncthreads();   // staging of next chunk complete; all reads of B done
  }

#pragma unroll
  for (int rt = 0; rt < 2; ++rt)
#pragma unroll
    for (int r = 0; r < 4; ++r) {
      float v = sacc[rt][r];
#pragma unroll
      for (int off = 1; off < 16; off <<= 1) v += __shfl_xor(v, off, 64);
      if (cL == 0)
        ps[(size_t)(r0 + wid * 32 + rt * 16 + quad * 4 + r) * 4 + cb] = v;
    }
}

// ---------------- Kernel 3: per-row loss + block reduce ----------------
__global__ __launch_bounds__(256) void k_combine(
    const float* __restrict__ ps, const float* __restrict__ simpos,
    const float* __restrict__ wptr, const float* __restrict__ bptr,
    float* __restrict__ p2) {
  __shared__ float red[4];
  const int tid = threadIdx.x;
  const int row = blockIdx.x * 256 + tid;
  const float wp = softplusf(wptr[0]), bv = bptr[0];
  const float4 s4 = *(const float4*)(ps + (size_t)row * 4);
  const float s = (s4.x + s4.y) + (s4.z + s4.w);
  float v = logf(s) - fmaf(wp, simpos[row], bv);
#pragma unroll
  for (int off = 32; off > 0; off >>= 1) v += __shfl_xor(v, off, 64);
  if ((tid & 63) == 0) red[tid >> 6] = v;
  __syncthreads();
  if (tid == 0) p2[blockIdx.x] = red[0] + red[1] + red[2] + red[3];
}

__global__ __launch_bounds__(64) void k_fin(const float* __restrict__ p2,
                                            float* __restrict__ out) {
  const int tid = threadIdx.x;
  float v = p2[tid];
#pragma unroll
  for (int off = 32; off > 0; off >>= 1) v += __shfl_xor(v, off, 64);
  if (tid == 0) out[0] = v * (1.0f / RR);
}

extern "C" void kernel_launch(void* const* d_in, const int* in_sizes, int n_in,
                              void* d_out, int out_size, void* d_ws, size_t ws_size,
                              hipStream_t stream) {
  const float* x = (const float*)d_in[0];
  const float* w = (const float*)d_in[1];
  const float* b = (const float*)d_in[2];
  float* out = (float*)d_out;

  const size_t xn_bytes = (size_t)RR * DD * 2;            // 16 MB
  const size_t rest = (size_t)CC * DD * 2 + (size_t)RR * 4 * 2 +
                      (size_t)RR * 4 * 4 + 64 * 4;
  const bool use_xn = ws_size >= xn_bytes + rest + 256;

  char* base = (char*)d_ws;
  ushort_t* xn = use_xn ? (ushort_t*)base : nullptr;
  char* p = base + (use_xn ? xn_bytes : 0);
  ushort_t* mn = (ushort_t*)p;  p += (size_t)CC * DD * 2;
  float* nx     = (float*)p;    p += (size_t)RR * 4;
  float* simpos = (float*)p;    p += (size_t)RR * 4;
  float* ps     = (float*)p;    p += (size_t)RR * 4 * 4;
  float* p2     = (float*)p;

  k_pre<<<CC, 256, 0, stream>>>(x, (unsigned*)mn, nx, simpos, xn);
  if (use_xn)
    k_gemm<true><<<512, 256, 0, stream>>>(x, xn, mn, nx, simpos, w, b, ps);
  else
    k_gemm<false><<<512, 256, 0, stream>>>(x, xn, mn, nx, simpos, w, b, ps);
  k_combine<<<RR / 256, 256, 0, stream>>>(ps, simpos, w, b, p2);
  k_fin<<<1, 64, 0, stream>>>(p2, out);
}